// Round 5
// baseline (271.801 us; speedup 1.0000x reference)
//
#include <hip/hip_runtime.h>
#include <hip/hip_bf16.h>

// RangeLoss: mean((preds - adjusted_target)^2) over 8M x 4 fp32.
// Memory-bound streaming reduction: 256 MB read, 1 float out.
// R4 evidence: VGPR=12 -> no pipelining, 2KB/wave in flight, 2.6 TB/s eff.
// R5 fix: unroll grid-stride x4, issue 8 dwordx4 loads before first use.

#define BLOCK 256
#define GRID 2048
#define CR 0.05f

__device__ __forceinline__ float row_loss(float4 p, float4 t)
{
    // --- _adjust_target, columns 0 and 1 (sequential semantics) ---
    float t0 = t.x;
    if (fabsf(p.x) < 0.01f && t0 == 0.0f) t0 = p.x;
    if (p.x > 0.99f && p.x < 1.01f && t0 == 1.0f) t0 = p.x;

    float t1 = t.y;
    if (fabsf(p.y) < 0.01f && t1 == 0.0f) t1 = p.y;
    if (p.y > 0.99f && p.y < 1.01f && t1 == 1.0f) t1 = p.y;

    // --- confidence-range override on column 1 (original p1/p2, adjusted t1) ---
    bool cond_hi  = p.z > 0.9f;
    bool cond_rng = (p.y * (1.0f + CR) > t1) && (p.y * (1.0f - CR) < t1);
    if (cond_hi || cond_rng) t1 = p.y;

    float d0 = p.x - t0;
    float d1 = p.y - t1;
    float d2 = p.z - t.z;
    float d3 = p.w - t.w;
    return d0 * d0 + d1 * d1 + d2 * d2 + d3 * d3;
}

__global__ __launch_bounds__(BLOCK) void range_loss_partial(
    const float4* __restrict__ preds,
    const float4* __restrict__ targ,
    float* __restrict__ partials,
    int nrows)
{
    const int tid = blockIdx.x * BLOCK + threadIdx.x;
    const int S = GRID * BLOCK;   // grid stride in rows

    float acc = 0.0f;
    int i = tid;

    // Unrolled-by-4 grid-stride: 8 independent dwordx4 loads in flight
    // (8 KB/wave) before any consumer -> 4x the MLP of the R4 kernel.
    for (; i + 3 * S < nrows; i += 4 * S) {
        float4 p0 = preds[i];
        float4 p1 = preds[i + S];
        float4 p2 = preds[i + 2 * S];
        float4 p3 = preds[i + 3 * S];
        float4 t0 = targ[i];
        float4 t1 = targ[i + S];
        float4 t2 = targ[i + 2 * S];
        float4 t3 = targ[i + 3 * S];
        acc += row_loss(p0, t0);
        acc += row_loss(p1, t1);
        acc += row_loss(p2, t2);
        acc += row_loss(p3, t3);
    }
    // tail: at most 3 single steps
    for (; i < nrows; i += S)
        acc += row_loss(preds[i], targ[i]);

    // wave (64-lane) reduction
    for (int off = 32; off > 0; off >>= 1)
        acc += __shfl_down(acc, off);

    __shared__ float smem[BLOCK / 64];
    int lane = threadIdx.x & 63;
    int wave = threadIdx.x >> 6;
    if (lane == 0) smem[wave] = acc;
    __syncthreads();

    if (threadIdx.x == 0) {
        float s = 0.0f;
        #pragma unroll
        for (int w = 0; w < BLOCK / 64; ++w) s += smem[w];
        partials[blockIdx.x] = s;
    }
}

__global__ __launch_bounds__(BLOCK) void range_loss_final(
    const float* __restrict__ partials,
    int nparts,
    float* __restrict__ out,
    double inv_n)
{
    double acc = 0.0;
    for (int i = threadIdx.x; i < nparts; i += BLOCK)
        acc += (double)partials[i];

    for (int off = 32; off > 0; off >>= 1)
        acc += __shfl_down(acc, off);

    __shared__ double smem[BLOCK / 64];
    int lane = threadIdx.x & 63;
    int wave = threadIdx.x >> 6;
    if (lane == 0) smem[wave] = acc;
    __syncthreads();

    if (threadIdx.x == 0) {
        double s = 0.0;
        #pragma unroll
        for (int w = 0; w < BLOCK / 64; ++w) s += smem[w];
        out[0] = (float)(s * inv_n);
    }
}

extern "C" void kernel_launch(void* const* d_in, const int* in_sizes, int n_in,
                              void* d_out, int out_size, void* d_ws, size_t ws_size,
                              hipStream_t stream)
{
    const float4* preds = (const float4*)d_in[0];
    const float4* targ  = (const float4*)d_in[1];

    int n_elems = in_sizes[0];     // 32,000,000
    int nrows   = n_elems / 4;     // 8,000,000 rows of float4

    float* partials = (float*)d_ws;            // GRID floats = 8 KB scratch
    float* out      = (float*)d_out;

    double inv_n = 1.0 / (double)n_elems;

    range_loss_partial<<<GRID, BLOCK, 0, stream>>>(preds, targ, partials, nrows);
    range_loss_final<<<1, BLOCK, 0, stream>>>(partials, GRID, out, inv_n);
}